// Round 8
// baseline (623.395 us; speedup 1.0000x reference)
//
#include <hip/hip_runtime.h>
#include <cstdint>

#define NN 16000
#define KK 16
#define FIN 32
#define HH 64
#define NE (NN*KK)
#define GG 32                    // 15.6 pts/cell; 3x3 rect -> stop-radius lambda~49 >> 16
#define NCELL (GG*GG)

#define NBLK 1000                // persistent grid: launch_bounds(256,4) -> 4 blk/CU -> 1024 cap
#define KNNB 250                 // knn blocks: 64 nodes/block (4 lanes/node)

// Device-scope spin barrier for a fully-resident grid (plain launch, graph-safe).
// Release: __threadfence + atomicAdd arrive. Poll: lane0 only, s_sleep backoff.
// Acquire: __threadfence after release observed. Monotonic targets; counter
// zeroed by host memset each iteration.
__device__ __forceinline__ void gbar(unsigned* bar, unsigned target) {
  __syncthreads();
  if (threadIdx.x == 0) {
    __threadfence();
    atomicAdd(bar, 1u);
    while (atomicAdd(bar, 0u) < target) __builtin_amdgcn_s_sleep(32);
    __threadfence();
  }
  __syncthreads();
}

// One persistent kernel, 6 phases, 5 grid barriers. All phase bodies are the
// R7-proven kernels verbatim (bit-identical numerics). Changes vs R7:
//  - prefix scan recomputed REDUNDANTLY per block into LDS (lds_cs): removes a
//    barrier and the global cstart/cursor buffers; knn span bounds then read
//    from LDS (cuts bound-load latency from knn's serial chain).
//  - scatter is atomic-free: rank captured from phase-A histogram atomicAdd,
//    position = lds_cs[cell] + rank (pack/cellid buffers eliminated, values
//    carried in registers across the barrier).
__global__ __launch_bounds__(256, 4) void mega_kernel(
    const float* __restrict__ c,   const float* __restrict__ x,
    const float* __restrict__ W1,  const float* __restrict__ b1,
    const float* __restrict__ W2,  const float* __restrict__ b2,
    const float* __restrict__ Wfc, const float* __restrict__ bfc,
    float* __restrict__ out,
    float4* __restrict__ sorted,   int* __restrict__ sid,
    int* __restrict__ nbr,         float* __restrict__ de,
    float* __restrict__ dis,       unsigned* __restrict__ gmm,
    float* __restrict__ xw1,       float* __restrict__ xw2,
    unsigned* __restrict__ cnt,    unsigned* __restrict__ bar) {
#pragma clang fp contract(off)
  __shared__ unsigned lds_cs[NCELL + 1];
  __shared__ unsigned wsum[4];
  const int bid = blockIdx.x, tid = threadIdx.x;
  const int gid = bid * 256 + tid;
  const int lane = tid & 63, wv = tid >> 6;

  // ---------------- Phase A: coords + cell + rank (registers) + histogram
  float my_x = 0.f, my_y = 0.f, my_sq = 0.f;
  unsigned my_cell = 0, my_rank = 0;
  if (gid == 0) { gmm[0] = 0x7F800000u; gmm[1] = 0u; }  // min=+inf bits, max=0
  if (gid < NN) {
    float xv = c[2*gid], yv = c[2*gid+1];
    float xx = xv * xv;            // round(x^2)  (no fma: contract off)
    float yy = yv * yv;            // round(y^2)
    my_x = xv; my_y = yv;
    my_sq = xx + yy;               // round(xx+yy)
    int cx = (int)(xv * GG); cx = cx > GG-1 ? GG-1 : (cx < 0 ? 0 : cx);
    int cy = (int)(yv * GG); cy = cy > GG-1 ? GG-1 : (cy < 0 ? 0 : cy);
    my_cell = (unsigned)(cy * GG + cx);
    my_rank = atomicAdd(&cnt[my_cell], 1u);
  }
  gbar(bar, 1u * NBLK);

  // ---------------- Phase B: redundant per-block scan of cnt -> lds_cs
  {
    unsigned h0 = cnt[tid*4+0], h1 = cnt[tid*4+1], h2 = cnt[tid*4+2], h3 = cnt[tid*4+3];
    unsigned s = h0 + h1 + h2 + h3;
    unsigned v = s;
#pragma unroll
    for (int off = 1; off < 64; off <<= 1) {
      unsigned u = __shfl_up(v, off, 64);
      if (lane >= off) v += u;
    }
    if (lane == 63) wsum[wv] = v;
    __syncthreads();
    if (wv == 0) {
      unsigned t = (lane < 4) ? wsum[lane] : 0u;
      unsigned vv = t;
#pragma unroll
      for (int off = 1; off < 4; off <<= 1) {
        unsigned u = __shfl_up(vv, off, 64);
        if (lane >= off) vv += u;
      }
      if (lane < 4) wsum[lane] = vv - t;           // exclusive
    }
    __syncthreads();
    unsigned b = wsum[wv] + v - s;
    lds_cs[tid*4+0] = b; b += h0;
    lds_cs[tid*4+1] = b; b += h1;
    lds_cs[tid*4+2] = b; b += h2;
    lds_cs[tid*4+3] = b; b += h3;
    if (tid == 255) lds_cs[NCELL] = b;             // == NN
    __syncthreads();
  }

  // ---------------- Phase C: atomic-free scatter from registers
  if (gid < NN) {
    unsigned p = lds_cs[my_cell] + my_rank;
    sorted[p] = make_float4(my_x, my_y, my_sq, __uint_as_float((unsigned)gid));
    sid[p] = gid;
  }
  gbar(bar, 2u * NBLK);

  // ---------------- Phase D: knn (bid<250) | gemm1 (250<=bid<750)
  if (bid < KNNB) {
    const int g = gid;
    const int t = g >> 2;                          // sorted node index
    const int q = g & 3;                           // quad lane
    const float4 me = sorted[t];
    const int myid = (int)__float_as_uint(me.w);
    const float h = 1.0f / GG;                     // exact 2^-5
    int cx = (int)(me.x * GG); cx = cx > GG-1 ? GG-1 : (cx < 0 ? 0 : cx);
    int cy = (int)(me.y * GG); cy = cy > GG-1 ? GG-1 : (cy < 0 ? 0 : cy);

    unsigned long long kd[KK];
#pragma unroll
    for (int m = 0; m < KK; ++m) kd[m] = ~0ull;

    auto process = [&](float4 cand) {
      int j = (int)__float_as_uint(cand.w);
      float xprod = me.x * cand.x;                       // round(x_i*x_j)
      float dot   = __builtin_fmaf(me.y, cand.y, xprod); // BLAS K=2 fma
      float S     = me.z + cand.z;                       // round(sq_i+sq_j)
      float twod  = dot + dot;                           // exact *2
      float d2    = S - twod;                            // one rounding
      unsigned ub = __float_as_uint(d2);
      ub = (ub & 0x80000000u) ? ~ub : (ub | 0x80000000u);
      unsigned long long key = ((unsigned long long)ub << 32) | (unsigned)j;
      if (j != myid && key < kd[KK-1]) {
        unsigned long long ck = key;
#pragma unroll
        for (int m = 0; m < KK; ++m) {
          bool sw = ck < kd[m];
          unsigned long long lo = sw ? ck : kd[m];
          unsigned long long hi = sw ? kd[m] : ck;
          kd[m] = lo; ck = hi;
        }
      }
    };
    // 2-deep pipelined span scan; bounds from LDS; 3 call sites
    auto scanSpan = [&](unsigned p0, unsigned p1) {
      unsigned pp = p0 + (unsigned)q;
      if (pp >= p1) return;
      float4 cur = sorted[pp];
      unsigned pn = pp + 4;
#pragma unroll 1
      while (pn < p1) {
        float4 nxt = sorted[pn];
        process(cur);
        cur = nxt;
        pn += 4;
      }
      process(cur);
    };

    // initial 3x3 rect (site 1)
    int lxa = cx-1 < 0 ? 0 : cx-1;
    int lxb = cx+1 > GG-1 ? GG-1 : cx+1;
    int lya = cy-1 < 0 ? 0 : cy-1;
    int lyb = cy+1 > GG-1 ? GG-1 : cy+1;
    {
      unsigned b0 = lds_cs[lya*GG + lxa];
      unsigned b1 = lds_cs[lya*GG + lxb + 1];
#pragma unroll 1
      for (int y = lya; y <= lyb; ++y) {
        unsigned n0 = 0, n1 = 0;
        if (y < lyb) { n0 = lds_cs[(y+1)*GG + lxa]; n1 = lds_cs[(y+1)*GG + lxb + 1]; }
        scanSpan(b0, b1);
        b0 = n0; b1 = n1;
      }
    }

    // ring expansion with exact count-based stop (validated; generic in h)
    int R = 1;
    while (true) {
      bool whole = (lxa <= 0) && (lxb >= GG-1) && (lya <= 0) && (lyb >= GG-1);
      bool done = whole;
      if (!done) {
        float edge = 1e30f;
        if (lxa > 0)    edge = fminf(edge, me.x - (float)lxa * h);
        if (lxb < GG-1) edge = fminf(edge, (float)(lxb+1) * h - me.x);
        if (lya > 0)    edge = fminf(edge, me.y - (float)lya * h);
        if (lyb < GG-1) edge = fminf(edge, (float)(lyb+1) * h - me.y);
        float lim = edge * edge - 1e-5f;           // margin >> Gram noise (~1e-6)
        if (lim > 0.0f) {
          unsigned lb = __float_as_uint(lim) | 0x80000000u;   // map(lim), lim>0
          int cle = 0;
#pragma unroll
          for (int m = 0; m < KK; ++m) cle += ((unsigned)(kd[m] >> 32) <= lb) ? 1 : 0;
          cle += __shfl_xor(cle, 1, 64);
          cle += __shfl_xor(cle, 2, 64);
          done = cle >= KK;
        }
      }
      if (done) break;
      ++R;
      int nxa = cx-R < 0 ? 0 : cx-R;
      int nxb = cx+R > GG-1 ? GG-1 : cx+R;
      int nya = cy-R < 0 ? 0 : cy-R;
      int nyb = cy+R > GG-1 ? GG-1 : cy+R;
      // new top/bottom rows (site 2)
#pragma unroll 1
      for (int rr = 0; rr < 2; ++rr) {
        int y = rr ? nyb : nya;
        bool has = rr ? (nyb > lyb) : (nya < lya);
        if (has) {
          unsigned p0 = lds_cs[y*GG + nxa];
          unsigned p1 = lds_cs[y*GG + nxb + 1];
          scanSpan(p0, p1);
        }
      }
      // new left/right columns (site 3)
#pragma unroll 1
      for (int ss = 0; ss < 2; ++ss) {
        int xcol = ss ? nxb : nxa;
        bool has = ss ? (nxb > lxb) : (nxa < lxa);
        if (has) {
          unsigned b0 = lds_cs[lya*GG + xcol];
          unsigned b1 = lds_cs[lya*GG + xcol + 1];
#pragma unroll 1
          for (int y = lya; y <= lyb; ++y) {
            unsigned n0 = 0, n1 = 0;
            if (y < lyb) { n0 = lds_cs[(y+1)*GG + xcol]; n1 = lds_cs[(y+1)*GG + xcol + 1]; }
            scanSpan(b0, b1);
            b0 = n0; b1 = n1;
          }
        }
      }
      lxa = nxa; lxb = nxb; lya = nya; lyb = nyb;
    }

    // merge 4 sorted per-lane lists -> global top-16 (keys unique via j bits)
    unsigned res[4];
#pragma unroll 1
    for (int r = 0; r < KK; ++r) {
      unsigned long long md = kd[0];
      unsigned long long m1 = __shfl_xor(md, 1, 64); md = m1 < md ? m1 : md;
      unsigned long long m2 = __shfl_xor(md, 2, 64); md = m2 < md ? m2 : md;
      if (kd[0] == md) {                            // unique winner lane pops
#pragma unroll
        for (int m = 0; m < KK-1; ++m) kd[m] = kd[m+1];
        kd[KK-1] = ~0ull;
      }
      if ((r >> 2) == q) res[r & 3] = (unsigned)(md & 0xFFFFFFFFull);
    }

    // write nbr + edge epilogue (identical ops to passing rounds)
    int4 w4; w4.x = (int)res[0]; w4.y = (int)res[1]; w4.z = (int)res[2]; w4.w = (int)res[3];
    *(int4*)(nbr + myid*KK + 4*q) = w4;
    unsigned bmin = 0xFFFFFFFFu, bmax = 0u;
#pragma unroll
    for (int e = 0; e < 4; ++e) {
      int j = (int)res[e];
      float dx = me.x - c[2*j];
      float dy = me.y - c[2*j+1];
      float xx = dx * dx;
      float yy = dy * dy;
      float d  = __builtin_sqrtf(xx + yy);
      de[myid*KK + 4*q + e] = d;
      unsigned bb = __float_as_uint(d);             // d >= 0: bit order == float order
      bmin = bmin < bb ? bmin : bb;
      bmax = bmax > bb ? bmax : bb;
    }
#pragma unroll
    for (int off = 32; off > 0; off >>= 1) {
      unsigned ob = __shfl_xor(bmin, off, 64);
      bmin = bmin < ob ? bmin : ob;
      unsigned oB = __shfl_xor(bmax, off, 64);
      bmax = bmax > oB ? bmax : oB;
    }
    if (lane == 0) {
      atomicMin(&gmm[0], bmin);
      atomicMax(&gmm[1], bmax);
    }
  } else if (bid < 750) {
    // gemm1: xw1 = x @ W1, 8 features/thread (500 blocks); per-feature fmaf
    // chain in ascending k == 4-feat version's order -> bit-identical
    int g2 = (bid - KNNB) * 256 + tid;
    int i = g2 >> 3, fq2 = g2 & 7;
    const float4* ar = (const float4*)(x + i * FIN);
    float4 A[FIN/4];
#pragma unroll
    for (int qq = 0; qq < FIN/4; ++qq) A[qq] = ar[qq];
    float4 acc0 = make_float4(0.f, 0.f, 0.f, 0.f);
    float4 acc1 = make_float4(0.f, 0.f, 0.f, 0.f);
#pragma unroll
    for (int k = 0; k < FIN; ++k) {
      float av = ((const float*)A)[k];
      float4 w0 = *(const float4*)(W1 + k*HH + 8*fq2);
      float4 w1v = *(const float4*)(W1 + k*HH + 8*fq2 + 4);
      acc0.x = fmaf(av, w0.x, acc0.x);
      acc0.y = fmaf(av, w0.y, acc0.y);
      acc0.z = fmaf(av, w0.z, acc0.z);
      acc0.w = fmaf(av, w0.w, acc0.w);
      acc1.x = fmaf(av, w1v.x, acc1.x);
      acc1.y = fmaf(av, w1v.y, acc1.y);
      acc1.z = fmaf(av, w1v.z, acc1.z);
      acc1.w = fmaf(av, w1v.w, acc1.w);
    }
    *(float4*)(xw1 + i*HH + 8*fq2)     = acc0;
    *(float4*)(xw1 + i*HH + 8*fq2 + 4) = acc1;
  }
  gbar(bar, 3u * NBLK);

  // ---------------- Phase E: ew + deg + dis
  if (gid < NN) {
    float mx  = __uint_as_float(gmm[1]);
    float rng = mx - __uint_as_float(gmm[0]);
    float deg = 0.0f;                       // edges first, self-loop last
    float4* dp = (float4*)(de + gid*KK);
#pragma unroll
    for (int qq = 0; qq < 4; ++qq) {
      float4 v = dp[qq];
      float e0 = (mx - v.x) / rng;
      float e1 = (mx - v.y) / rng;
      float e2 = (mx - v.z) / rng;
      float e3 = (mx - v.w) / rng;
      deg = deg + e0; deg = deg + e1;
      deg = deg + e2; deg = deg + e3;
      dp[qq] = make_float4(e0, e1, e2, e3);
    }
    deg = deg + 1.0f;                       // self-loop weight 1, added last
    dis[gid] = 1.0f / __builtin_sqrtf(deg); // deg >= 1
  }
  gbar(bar, 4u * NBLK);

  // ---------------- Phase F: agg1 + relu + gemm2 (4 nodes per wave, 4 reps)
  {
    const float* ew = de;                   // de holds ew after phase E
    int w = bid * 4 + wv;                   // 4000 wave ids
#pragma unroll 1
    for (int rep = 0; rep < 4; ++rep) {
      int i = sid[w + rep*4000];
      float di = dis[i];
      float acc = 0.0f;
#pragma unroll 4
      for (int k = 0; k < KK; ++k) {
        int s = nbr[i*KK + k];
        float coef = (dis[s] * ew[i*KK + k]) * di;   // (dis[s]*w)*dis[t]
        acc = fmaf(coef, xw1[s*HH + lane], acc);
      }
      acc = fmaf(di * di, xw1[i*HH + lane], acc);    // self loop last
      float hv = fmaxf(acc + b1[lane], 0.0f);        // h1[i][lane]
      float acc2 = 0.0f;
#pragma unroll 16
      for (int k = 0; k < HH; ++k) {
        float hk = __shfl(hv, k, 64);
        acc2 = fmaf(hk, W2[k*HH + lane], acc2);
      }
      xw2[i*HH + lane] = acc2;
    }
  }
  gbar(bar, 5u * NBLK);

  // ---------------- Phase G: agg2 + relu + fc
  {
    const float* ew = de;
    int w = bid * 4 + wv;
#pragma unroll 1
    for (int rep = 0; rep < 4; ++rep) {
      int i = sid[w + rep*4000];
      float di = dis[i];
      float acc = 0.0f;
#pragma unroll 4
      for (int k = 0; k < KK; ++k) {
        int s = nbr[i*KK + k];
        float coef = (dis[s] * ew[i*KK + k]) * di;
        acc = fmaf(coef, xw2[s*HH + lane], acc);
      }
      acc = fmaf(di * di, xw2[i*HH + lane], acc);
      float v = fmaxf(acc + b2[lane], 0.0f);         // h2 feature
      float p = v * Wfc[lane];                       // h2 @ Wfc  (F_OUT = 1)
#pragma unroll
      for (int off = 32; off > 0; off >>= 1) p = p + __shfl_xor(p, off, 64);
      if (lane == 0) out[i] = p + bfc[0];
    }
  }
}

// ---------------------------------------------------------------- launch
extern "C" void kernel_launch(void* const* d_in, const int* in_sizes, int n_in,
                              void* d_out, int out_size, void* d_ws, size_t ws_size,
                              hipStream_t stream) {
  (void)in_sizes; (void)n_in; (void)out_size; (void)ws_size;
  const float* x   = (const float*)d_in[0];
  const float* c   = (const float*)d_in[1];
  const float* W1  = (const float*)d_in[2];
  const float* b1  = (const float*)d_in[3];
  const float* W2  = (const float*)d_in[4];
  const float* b2  = (const float*)d_in[5];
  const float* Wfc = (const float*)d_in[6];
  const float* bfc = (const float*)d_in[7];
  float* out = (float*)d_out;

  char* ws = (char*)d_ws;
  size_t off = 0;
  auto alloc = [&](size_t bytes) -> void* {
    void* p = ws + off;
    off += (bytes + 255) & ~size_t(255);
    return p;
  };
  float4*   sorted = (float4*)  alloc(NN * sizeof(float4));       // 256 KB
  int*      sid    = (int*)     alloc(NN * sizeof(int));          // 64 KB
  int*      nbr    = (int*)     alloc(NE * sizeof(int));          // 1 MB
  float*    de     = (float*)   alloc(NE * sizeof(float));        // 1 MB (d then ew in-place)
  float*    dis    = (float*)   alloc(NN * sizeof(float));        // 64 KB
  unsigned* gmm    = (unsigned*)alloc(2 * sizeof(unsigned));
  float*    xw1    = (float*)   alloc(NN * HH * sizeof(float));   // 4 MB
  float*    xw2    = (float*)   alloc(NN * HH * sizeof(float));   // 4 MB
  unsigned* ctrl   = (unsigned*)alloc((NCELL + 64) * sizeof(unsigned)); // cnt + bar
  unsigned* cnt    = ctrl;
  unsigned* bar    = ctrl + NCELL;

  hipMemsetAsync(ctrl, 0, (NCELL + 64) * sizeof(unsigned), stream);
  mega_kernel<<<NBLK, 256, 0, stream>>>(c, x, W1, b1, W2, b2, Wfc, bfc, out,
                                        sorted, sid, nbr, de, dis, gmm,
                                        xw1, xw2, cnt, bar);
}

// Round 9
// 153.419 us; speedup vs baseline: 4.0634x; 4.0634x over previous
//
#include <hip/hip_runtime.h>
#include <cstdint>

#define NN 16000
#define KK 16
#define FIN 32
#define HH 64
#define NE (NN*KK)
#define GG 32                    // 15.6 pts/cell; 3x3 rect -> stop-radius lambda~49 >> 16
#define NCELL (GG*GG)

#define KNNB 250                 // knn blocks: 64 nodes/block (4 lanes/node)
#define GEMM1B (NN*16/256)       // 1000 gemm1 blocks
#define PF 16                    // prefetch slots/lane: covers T<=64 (P(T>64)~0.6%)

// ---------------------------------------------------------------- prep + count
// rank packed into cellid: cell in bits[9:0], rank in bits[31:10] (rank<16000)
__global__ __launch_bounds__(256) void prep_count_kernel(const float* __restrict__ c,
                                                         float4* __restrict__ pack,
                                                         unsigned* __restrict__ cellid,
                                                         unsigned* __restrict__ cnt,
                                                         unsigned* __restrict__ gmm) {
#pragma clang fp contract(off)
  int i = blockIdx.x * 256 + threadIdx.x;
  if (i == 0) { gmm[0] = 0x7F800000u; gmm[1] = 0u; }  // min=+inf bits, max=0 (d>=0)
  if (i >= NN) return;
  float xv = c[2*i], yv = c[2*i+1];
  float xx = xv * xv;            // round(x^2)  (no fma: contract off)
  float yy = yv * yv;            // round(y^2)
  float sq = xx + yy;            // round(xx+yy)
  pack[i] = make_float4(xv, yv, sq, __uint_as_float((unsigned)i));
  int cx = (int)(xv * GG); cx = cx > GG-1 ? GG-1 : (cx < 0 ? 0 : cx);
  int cy = (int)(yv * GG); cy = cy > GG-1 ? GG-1 : (cy < 0 ? 0 : cy);
  unsigned cell = (unsigned)(cy * GG + cx);
  unsigned rank = atomicAdd(&cnt[cell], 1u);
  cellid[i] = cell | (rank << 10);
}

// ---------------------------------------------------------------- scatter (atomic-free) + redundant LDS scan
// Each block scans the 1024-cell histogram into LDS (R8-phase-B-proven code);
// block 0 also publishes cstart for knn. Position = cs[cell] + rank.
__global__ __launch_bounds__(256) void scatter_kernel(const float4* __restrict__ pack,
                                                      const unsigned* __restrict__ cellid,
                                                      const unsigned* __restrict__ cnt,
                                                      unsigned* __restrict__ cstart,
                                                      float4* __restrict__ sorted,
                                                      int* __restrict__ sid) {
  __shared__ unsigned lds_cs[NCELL + 1];
  __shared__ unsigned wsum[4];
  const int tid = threadIdx.x;
  const int lane = tid & 63, wv = tid >> 6;
  {
    unsigned h0 = cnt[tid*4+0], h1 = cnt[tid*4+1], h2 = cnt[tid*4+2], h3 = cnt[tid*4+3];
    unsigned s = h0 + h1 + h2 + h3;
    unsigned v = s;
#pragma unroll
    for (int off = 1; off < 64; off <<= 1) {
      unsigned u = __shfl_up(v, off, 64);
      if (lane >= off) v += u;
    }
    if (lane == 63) wsum[wv] = v;
    __syncthreads();
    if (wv == 0) {
      unsigned t = (lane < 4) ? wsum[lane] : 0u;
      unsigned vv = t;
#pragma unroll
      for (int off = 1; off < 4; off <<= 1) {
        unsigned u = __shfl_up(vv, off, 64);
        if (lane >= off) vv += u;
      }
      if (lane < 4) wsum[lane] = vv - t;           // exclusive
    }
    __syncthreads();
    unsigned b = wsum[wv] + v - s;
    lds_cs[tid*4+0] = b; b += h0;
    lds_cs[tid*4+1] = b; b += h1;
    lds_cs[tid*4+2] = b; b += h2;
    lds_cs[tid*4+3] = b; b += h3;
    if (tid == 255) lds_cs[NCELL] = b;             // == NN
    __syncthreads();
    if (blockIdx.x == 0) {
      cstart[tid*4+0] = lds_cs[tid*4+0];
      cstart[tid*4+1] = lds_cs[tid*4+1];
      cstart[tid*4+2] = lds_cs[tid*4+2];
      cstart[tid*4+3] = lds_cs[tid*4+3];
      if (tid == 255) cstart[NCELL] = lds_cs[NCELL];
    }
  }
  int i = blockIdx.x * 256 + tid;
  if (i >= NN) return;
  unsigned cc = cellid[i];
  unsigned p = lds_cs[cc & 1023u] + (cc >> 10);
  sorted[p] = pack[i];                             // .w carries original index bits
  sid[p] = i;
}

// ---------------------------------------------------------------- knn (3x3 flat prefetch) + gemm1 backfill
// R8 analysis: knn waves are ~80% memory-wait (~100 serial round-trips) --
// loads sat in dependent divergent loops. Here the whole 3x3 candidate set
// (T~47) is issued as PF=16 static-unrolled INDEPENDENT loads per lane after
// one batched bound-load; flat idx->addr via 2-compare selects (registers
// only, R6 scratch lesson). Candidate union per quad identical to R7's 3
// row-spans -> merged top-16 and quad stop test partition-independent ->
// bit-identical results. T>64 continues mod-4 partition (no duplicates);
// rings (~never at GG=32) are the R7-proven fallback verbatim.
__global__ __launch_bounds__(256) void knn_gemm1_kernel(const float4* __restrict__ sorted,
                                                        const unsigned* __restrict__ cstart,
                                                        const float* __restrict__ c,
                                                        int* __restrict__ nbr,
                                                        float* __restrict__ de,
                                                        unsigned* __restrict__ gmm,
                                                        const float* __restrict__ xa_,
                                                        const float* __restrict__ w1,
                                                        float* __restrict__ xw1) {
#pragma clang fp contract(off)
  if (blockIdx.x >= KNNB) {
    // ---- gemm1: xw1 = x @ W1, KIN=32, 4 features/thread (R1-verbatim, proven)
    int gid = (blockIdx.x - KNNB) * 256 + threadIdx.x;   // NN*16 total
    int i = gid >> 4, fq = gid & 15;
    const float4* ar = (const float4*)(xa_ + i * FIN);
    float4 A[FIN/4];
#pragma unroll
    for (int qq = 0; qq < FIN/4; ++qq) A[qq] = ar[qq];
    float4 acc = make_float4(0.f, 0.f, 0.f, 0.f);
#pragma unroll
    for (int k = 0; k < FIN; ++k) {
      float av = ((const float*)A)[k];
      float4 wv4 = *(const float4*)(w1 + k*HH + 4*fq);
      acc.x = fmaf(av, wv4.x, acc.x);
      acc.y = fmaf(av, wv4.y, acc.y);
      acc.z = fmaf(av, wv4.z, acc.z);
      acc.w = fmaf(av, wv4.w, acc.w);
    }
    *(float4*)(xw1 + i*HH + 4*fq) = acc;
    return;
  }

  const int g = blockIdx.x * 256 + threadIdx.x;
  const int t = g >> 2;                            // sorted node index
  const int q = g & 3;                             // quad lane
  const int lane = threadIdx.x & 63;
  const float4 me = sorted[t];
  const int myid = (int)__float_as_uint(me.w);
  const float h = 1.0f / GG;                       // exact 2^-5
  int cx = (int)(me.x * GG); cx = cx > GG-1 ? GG-1 : (cx < 0 ? 0 : cx);
  int cy = (int)(me.y * GG); cy = cy > GG-1 ? GG-1 : (cy < 0 ? 0 : cy);

  unsigned long long kd[KK];
#pragma unroll
  for (int m = 0; m < KK; ++m) kd[m] = ~0ull;

  auto process = [&](float4 cand) {
    int j = (int)__float_as_uint(cand.w);
    float xprod = me.x * cand.x;                       // round(x_i*x_j)
    float dot   = __builtin_fmaf(me.y, cand.y, xprod); // BLAS K=2 fma
    float S     = me.z + cand.z;                       // round(sq_i+sq_j)
    float twod  = dot + dot;                           // exact *2
    float d2    = S - twod;                            // one rounding
    unsigned ub = __float_as_uint(d2);
    ub = (ub & 0x80000000u) ? ~ub : (ub | 0x80000000u);
    unsigned long long key = ((unsigned long long)ub << 32) | (unsigned)j;
    if (j != myid && key < kd[KK-1]) {
      unsigned long long ck = key;
#pragma unroll
      for (int m = 0; m < KK; ++m) {
        bool sw = ck < kd[m];
        unsigned long long lo = sw ? ck : kd[m];
        unsigned long long hi = sw ? kd[m] : ck;
        kd[m] = lo; ck = hi;
      }
    }
  };

  // ---- 3x3 rect as one flat prefetched stream
  int lxa = cx-1 < 0 ? 0 : cx-1;
  int lxb = cx+1 > GG-1 ? GG-1 : cx+1;
  int lya = cy-1 < 0 ? 0 : cy-1;
  int lyb = cy+1 > GG-1 ? GG-1 : cy+1;
  unsigned b0, l0, b1, l1, b2, l2;
  {
    int nr = lyb - lya + 1;                        // 2 or 3
    unsigned s0 = cstart[lya*GG + lxa];
    unsigned e0 = cstart[lya*GG + lxb + 1];
    unsigned s1 = cstart[(lya+1)*GG + lxa];
    unsigned e1 = cstart[(lya+1)*GG + lxb + 1];
    unsigned s2 = (nr > 2) ? cstart[(lya+2)*GG + lxa] : 0u;
    unsigned e2 = (nr > 2) ? cstart[(lya+2)*GG + lxb + 1] : 0u;
    b0 = s0; l0 = e0 - s0;
    b1 = s1; l1 = e1 - s1;
    b2 = s2; l2 = e2 - s2;                         // 0 when nr==2
  }
  const unsigned c01 = l0 + l1;
  const unsigned T = c01 + l2;
  auto mapAddr = [&](unsigned idx) -> unsigned {   // idx < T
    unsigned a = b0 + idx;
    unsigned a1 = b1 + (idx - l0);
    unsigned a2 = b2 + (idx - c01);
    a = (idx >= l0) ? a1 : a;
    a = (idx >= c01) ? a2 : a;
    return a;
  };
  {
    float4 A[PF];
#pragma unroll
    for (int d = 0; d < PF; ++d) {
      unsigned idx = (unsigned)q + 4u*d;
      unsigned a = (idx < T) ? mapAddr(idx) : 0u;  // safe dummy addr; masked below
      A[d] = sorted[a];
    }
#pragma unroll
    for (int d = 0; d < PF; ++d) {
      unsigned idx = (unsigned)q + 4u*d;
      if (idx < T) process(A[d]);
    }
    // rare overflow (T>64): continue same mod-4 partition, no duplicates
    unsigned idx = 4u*PF + (unsigned)q;
#pragma unroll 1
    while (idx < T) { process(sorted[mapAddr(idx)]); idx += 4u; }
  }

  // ---- ring expansion with exact count-based stop (R7-proven; ~never fires)
  auto scanSpan = [&](unsigned p0, unsigned p1) {
    unsigned pp = p0 + (unsigned)q;
    if (pp >= p1) return;
    float4 cur = sorted[pp];
    unsigned pn = pp + 4;
#pragma unroll 1
    while (pn < p1) {
      float4 nxt = sorted[pn];
      process(cur);
      cur = nxt;
      pn += 4;
    }
    process(cur);
  };
  int R = 1;
  while (true) {
    bool whole = (lxa <= 0) && (lxb >= GG-1) && (lya <= 0) && (lyb >= GG-1);
    bool done = whole;
    if (!done) {
      float edge = 1e30f;
      if (lxa > 0)    edge = fminf(edge, me.x - (float)lxa * h);
      if (lxb < GG-1) edge = fminf(edge, (float)(lxb+1) * h - me.x);
      if (lya > 0)    edge = fminf(edge, me.y - (float)lya * h);
      if (lyb < GG-1) edge = fminf(edge, (float)(lyb+1) * h - me.y);
      float lim = edge * edge - 1e-5f;             // margin >> Gram noise (~1e-6)
      if (lim > 0.0f) {
        unsigned lb = __float_as_uint(lim) | 0x80000000u;   // map(lim), lim>0
        int cle = 0;
#pragma unroll
        for (int m = 0; m < KK; ++m) cle += ((unsigned)(kd[m] >> 32) <= lb) ? 1 : 0;
        cle += __shfl_xor(cle, 1, 64);
        cle += __shfl_xor(cle, 2, 64);
        done = cle >= KK;
      }
    }
    if (done) break;
    ++R;
    int nxa = cx-R < 0 ? 0 : cx-R;
    int nxb = cx+R > GG-1 ? GG-1 : cx+R;
    int nya = cy-R < 0 ? 0 : cy-R;
    int nyb = cy+R > GG-1 ? GG-1 : cy+R;
    // new top/bottom rows
#pragma unroll 1
    for (int rr = 0; rr < 2; ++rr) {
      int y = rr ? nyb : nya;
      bool has = rr ? (nyb > lyb) : (nya < lya);
      if (has) {
        unsigned p0 = cstart[y*GG + nxa];
        unsigned p1 = cstart[y*GG + nxb + 1];
        scanSpan(p0, p1);
      }
    }
    // new left/right columns
#pragma unroll 1
    for (int ss = 0; ss < 2; ++ss) {
      int xcol = ss ? nxb : nxa;
      bool has = ss ? (nxb > lxb) : (nxa < lxa);
      if (has) {
        unsigned bb0 = cstart[lya*GG + xcol];
        unsigned bb1 = cstart[lya*GG + xcol + 1];
#pragma unroll 1
        for (int y = lya; y <= lyb; ++y) {
          unsigned n0 = 0, n1 = 0;
          if (y < lyb) { n0 = cstart[(y+1)*GG + xcol]; n1 = cstart[(y+1)*GG + xcol + 1]; }
          scanSpan(bb0, bb1);
          bb0 = n0; bb1 = n1;
        }
      }
    }
    lxa = nxa; lxb = nxb; lya = nya; lyb = nyb;
  }

  // ---- merge 4 sorted per-lane lists -> global top-16 (keys unique via j bits)
  unsigned res[4];
#pragma unroll 1
  for (int r = 0; r < KK; ++r) {
    unsigned long long md = kd[0];
    unsigned long long m1 = __shfl_xor(md, 1, 64); md = m1 < md ? m1 : md;
    unsigned long long m2 = __shfl_xor(md, 2, 64); md = m2 < md ? m2 : md;
    if (kd[0] == md) {                              // unique winner lane pops
#pragma unroll
    for (int m = 0; m < KK-1; ++m) kd[m] = kd[m+1];
      kd[KK-1] = ~0ull;
    }
    if ((r >> 2) == q) res[r & 3] = (unsigned)(md & 0xFFFFFFFFull);
  }

  // ---- write nbr + edge epilogue (identical ops to passing rounds)
  int4 w4; w4.x = (int)res[0]; w4.y = (int)res[1]; w4.z = (int)res[2]; w4.w = (int)res[3];
  *(int4*)(nbr + myid*KK + 4*q) = w4;
  unsigned bmin = 0xFFFFFFFFu, bmax = 0u;
#pragma unroll
  for (int e = 0; e < 4; ++e) {
    int j = (int)res[e];
    float dx = me.x - c[2*j];
    float dy = me.y - c[2*j+1];
    float xx = dx * dx;
    float yy = dy * dy;
    float d  = __builtin_sqrtf(xx + yy);
    de[myid*KK + 4*q + e] = d;
    unsigned bb = __float_as_uint(d);               // d >= 0: bit order == float order
    bmin = bmin < bb ? bmin : bb;
    bmax = bmax > bb ? bmax : bb;
  }
#pragma unroll
  for (int off = 32; off > 0; off >>= 1) {
    unsigned ob = __shfl_xor(bmin, off, 64);
    bmin = bmin < ob ? bmin : ob;
    unsigned oB = __shfl_xor(bmax, off, 64);
    bmax = bmax > oB ? bmax : oB;
  }
  if (lane == 0) {
    atomicMin(&gmm[0], bmin);
    atomicMax(&gmm[1], bmax);
  }
}

// ---------------------------------------------------------------- ew + deg + dis
__global__ __launch_bounds__(256) void ewdeg_kernel(const unsigned* __restrict__ gmm,
                                                    float* __restrict__ de,   // in: d, out: ew
                                                    float* __restrict__ dis) {
#pragma clang fp contract(off)
  int i = blockIdx.x * 256 + threadIdx.x;
  if (i >= NN) return;
  float mx  = __uint_as_float(gmm[1]);
  float rng = mx - __uint_as_float(gmm[0]);
  float deg = 0.0f;                         // edges first, self-loop last (segment_sum order)
  float4* dp = (float4*)(de + i*KK);
#pragma unroll
  for (int qq = 0; qq < 4; ++qq) {
    float4 v = dp[qq];
    float e0 = (mx - v.x) / rng;
    float e1 = (mx - v.y) / rng;
    float e2 = (mx - v.z) / rng;
    float e3 = (mx - v.w) / rng;
    deg = deg + e0; deg = deg + e1;
    deg = deg + e2; deg = deg + e3;
    dp[qq] = make_float4(e0, e1, e2, e3);
  }
  deg = deg + 1.0f;                         // self-loop weight 1, added last
  dis[i] = 1.0f / __builtin_sqrtf(deg);     // deg >= 1
}

// ---------------------------------------------------------------- agg1 + relu + gemm2 fused
__global__ __launch_bounds__(256) void agg_gemm2_kernel(const float* __restrict__ xw,
                                                        const int* __restrict__ nbr,
                                                        const float* __restrict__ ew,
                                                        const float* __restrict__ dis,
                                                        const float* __restrict__ b,
                                                        const int* __restrict__ sid,
                                                        const float* __restrict__ w2,
                                                        float* __restrict__ xw2) {
  int wv = threadIdx.x >> 6, lane = threadIdx.x & 63;
  int i = sid[(blockIdx.x << 2) + wv];
  float di = dis[i];
  float acc = 0.0f;
#pragma unroll 4
  for (int k = 0; k < KK; ++k) {
    int s = nbr[i*KK + k];
    float coef = (dis[s] * ew[i*KK + k]) * di;   // (dis[s]*w)*dis[t]
    acc = fmaf(coef, xw[s*HH + lane], acc);
  }
  acc = fmaf(di * di, xw[i*HH + lane], acc);     // self loop last
  float hv = fmaxf(acc + b[lane], 0.0f);         // h1[i][lane]
  float acc2 = 0.0f;
#pragma unroll 16
  for (int k = 0; k < HH; ++k) {
    float hk = __shfl(hv, k, 64);
    acc2 = fmaf(hk, w2[k*HH + lane], acc2);
  }
  xw2[i*HH + lane] = acc2;
}

// ---------------------------------------------------------------- agg2 + relu + fc (final)
__global__ __launch_bounds__(256) void agg_fc_kernel(const float* __restrict__ xw,
                                                     const int* __restrict__ nbr,
                                                     const float* __restrict__ ew,
                                                     const float* __restrict__ dis,
                                                     const float* __restrict__ b,
                                                     const float* __restrict__ wfc,
                                                     const float* __restrict__ bfc,
                                                     const int* __restrict__ sid,
                                                     float* __restrict__ out) {
  int wv = threadIdx.x >> 6, lane = threadIdx.x & 63;
  int i = sid[(blockIdx.x << 2) + wv];
  float di = dis[i];
  float acc = 0.0f;
#pragma unroll 4
  for (int k = 0; k < KK; ++k) {
    int s = nbr[i*KK + k];
    float coef = (dis[s] * ew[i*KK + k]) * di;
    acc = fmaf(coef, xw[s*HH + lane], acc);
  }
  acc = fmaf(di * di, xw[i*HH + lane], acc);
  float v = fmaxf(acc + b[lane], 0.0f);             // h2 feature
  float p = v * wfc[lane];                          // h2 @ Wfc  (F_OUT = 1)
#pragma unroll
  for (int off = 32; off > 0; off >>= 1) p = p + __shfl_xor(p, off, 64);
  if (lane == 0) out[i] = p + bfc[0];
}

// ---------------------------------------------------------------- launch
extern "C" void kernel_launch(void* const* d_in, const int* in_sizes, int n_in,
                              void* d_out, int out_size, void* d_ws, size_t ws_size,
                              hipStream_t stream) {
  (void)in_sizes; (void)n_in; (void)out_size; (void)ws_size;
  const float* x   = (const float*)d_in[0];
  const float* c   = (const float*)d_in[1];
  const float* W1  = (const float*)d_in[2];
  const float* b1  = (const float*)d_in[3];
  const float* W2  = (const float*)d_in[4];
  const float* b2  = (const float*)d_in[5];
  const float* Wfc = (const float*)d_in[6];
  const float* bfc = (const float*)d_in[7];
  float* out = (float*)d_out;

  char* ws = (char*)d_ws;
  size_t off = 0;
  auto alloc = [&](size_t bytes) -> void* {
    void* p = ws + off;
    off += (bytes + 255) & ~size_t(255);
    return p;
  };
  float4*   pack   = (float4*)  alloc(NN * sizeof(float4));       // 256 KB
  float4*   sorted = (float4*)  alloc(NN * sizeof(float4));       // 256 KB
  unsigned* cnt    = (unsigned*)alloc(NCELL * sizeof(unsigned));  // 4 KB
  unsigned* cstart = (unsigned*)alloc((NCELL+1) * sizeof(unsigned));
  unsigned* cellid = (unsigned*)alloc(NN * sizeof(unsigned));     // 64 KB
  int*      sid    = (int*)     alloc(NN * sizeof(int));          // 64 KB
  int*      nbr    = (int*)     alloc(NE * sizeof(int));          // 1 MB
  float*    ew     = (float*)   alloc(NE * sizeof(float));        // 1 MB (d then ew in-place)
  float*    dis    = (float*)   alloc(NN * sizeof(float));        // 64 KB
  unsigned* gmm    = (unsigned*)alloc(2 * sizeof(unsigned));
  float*    xw1    = (float*)   alloc(NN * HH * sizeof(float));   // 4 MB
  float*    xw2    = (float*)   alloc(NN * HH * sizeof(float));   // 4 MB

  const int NB = (NN + 255) / 256;
  hipMemsetAsync(cnt, 0, NCELL * sizeof(unsigned), stream);
  prep_count_kernel<<<NB,   256, 0, stream>>>(c, pack, cellid, cnt, gmm);
  scatter_kernel   <<<NB,   256, 0, stream>>>(pack, cellid, cnt, cstart, sorted, sid);
  knn_gemm1_kernel <<<KNNB + GEMM1B, 256, 0, stream>>>(sorted, cstart, c, nbr, ew, gmm,
                                                       x, W1, xw1);
  ewdeg_kernel     <<<NB,   256, 0, stream>>>(gmm, ew, dis);
  agg_gemm2_kernel <<<NN/4, 256, 0, stream>>>(xw1, nbr, ew, dis, b1, sid, W2, xw2);
  agg_fc_kernel    <<<NN/4, 256, 0, stream>>>(xw2, nbr, ew, dis, b2, Wfc, bfc, sid, out);
}

// Round 11
// 153.172 us; speedup vs baseline: 4.0699x; 1.0016x over previous
//
#include <hip/hip_runtime.h>
#include <cstdint>

#define NN 16000
#define KK 16
#define FIN 32
#define HH 64
#define NE (NN*KK)
#define GG 32                    // 15.6 pts/cell; 3x3 rect -> stop-radius lambda~49 >> 16
#define NCELL (GG*GG)

#define KNNB 250                 // knn blocks: 64 nodes/block (4 lanes/node)
#define GEMM1B (NN*16/256)       // 1000 gemm1 blocks
#define PF 16                    // prefetch slots/lane: covers T<=64 (P(T>64)~0.6%)

// ---------------------------------------------------------------- prep + count
// rank packed into cellid: cell in bits[9:0], rank in bits[31:10] (rank<16000)
__global__ __launch_bounds__(256) void prep_count_kernel(const float* __restrict__ c,
                                                         float4* __restrict__ pack,
                                                         unsigned* __restrict__ cellid,
                                                         unsigned* __restrict__ cnt,
                                                         unsigned* __restrict__ gmm) {
#pragma clang fp contract(off)
  int i = blockIdx.x * 256 + threadIdx.x;
  if (i == 0) { gmm[0] = 0x7F800000u; gmm[1] = 0u; }  // min=+inf bits, max=0 (d>=0)
  if (i >= NN) return;
  float xv = c[2*i], yv = c[2*i+1];
  float xx = xv * xv;            // round(x^2)  (no fma: contract off)
  float yy = yv * yv;            // round(y^2)
  float sq = xx + yy;            // round(xx+yy)
  pack[i] = make_float4(xv, yv, sq, __uint_as_float((unsigned)i));
  int cx = (int)(xv * GG); cx = cx > GG-1 ? GG-1 : (cx < 0 ? 0 : cx);
  int cy = (int)(yv * GG); cy = cy > GG-1 ? GG-1 : (cy < 0 ? 0 : cy);
  unsigned cell = (unsigned)(cy * GG + cx);
  unsigned rank = atomicAdd(&cnt[cell], 1u);
  cellid[i] = cell | (rank << 10);
}

// ---------------------------------------------------------------- scatter (atomic-free) + redundant LDS scan
// Each block scans the 1024-cell histogram into LDS (R8-phase-B-proven code);
// block 0 also publishes cstart for knn. Position = cs[cell] + rank.
__global__ __launch_bounds__(256) void scatter_kernel(const float4* __restrict__ pack,
                                                      const unsigned* __restrict__ cellid,
                                                      const unsigned* __restrict__ cnt,
                                                      unsigned* __restrict__ cstart,
                                                      float4* __restrict__ sorted,
                                                      int* __restrict__ sid) {
  __shared__ unsigned lds_cs[NCELL + 1];
  __shared__ unsigned wsum[4];
  const int tid = threadIdx.x;
  const int lane = tid & 63, wv = tid >> 6;
  {
    unsigned h0 = cnt[tid*4+0], h1 = cnt[tid*4+1], h2 = cnt[tid*4+2], h3 = cnt[tid*4+3];
    unsigned s = h0 + h1 + h2 + h3;
    unsigned v = s;
#pragma unroll
    for (int off = 1; off < 64; off <<= 1) {
      unsigned u = __shfl_up(v, off, 64);
      if (lane >= off) v += u;
    }
    if (lane == 63) wsum[wv] = v;
    __syncthreads();
    if (wv == 0) {
      unsigned t = (lane < 4) ? wsum[lane] : 0u;
      unsigned vv = t;
#pragma unroll
      for (int off = 1; off < 4; off <<= 1) {
        unsigned u = __shfl_up(vv, off, 64);
        if (lane >= off) vv += u;
      }
      if (lane < 4) wsum[lane] = vv - t;           // exclusive
    }
    __syncthreads();
    unsigned b = wsum[wv] + v - s;
    lds_cs[tid*4+0] = b; b += h0;
    lds_cs[tid*4+1] = b; b += h1;
    lds_cs[tid*4+2] = b; b += h2;
    lds_cs[tid*4+3] = b; b += h3;
    if (tid == 255) lds_cs[NCELL] = b;             // == NN
    __syncthreads();
    if (blockIdx.x == 0) {
      cstart[tid*4+0] = lds_cs[tid*4+0];
      cstart[tid*4+1] = lds_cs[tid*4+1];
      cstart[tid*4+2] = lds_cs[tid*4+2];
      cstart[tid*4+3] = lds_cs[tid*4+3];
      if (tid == 255) cstart[NCELL] = lds_cs[NCELL];
    }
  }
  int i = blockIdx.x * 256 + tid;
  if (i >= NN) return;
  unsigned cc = cellid[i];
  unsigned p = lds_cs[cc & 1023u] + (cc >> 10);
  sorted[p] = pack[i];                             // .w carries original index bits
  sid[p] = i;
}

// ---------------------------------------------------------------- knn (3x3 flat prefetch, forced) + gemm1 backfill
// R9 post-mortem: VGPR_Count=48 proves the compiler SANK the 16-load prefetch
// (can't hold kd[16]+A[16] in 48 regs) -- the latency experiment never ran.
// This version forces it: __launch_bounds__(256,1) frees the register budget
// (knn runs ~1 wave/SIMD anyway; gemm1 backfill tolerates lower occupancy),
// and the consume loop is BRANCH-FREE via a sentinel (out-of-range slots load
// sorted[0] with .w := me.w, so process() rejects them through the existing
// j!=myid test -- touches nothing, bit-exact). Candidate union per quad is
// unchanged -> merged top-16 and quad stop test partition-independent ->
// results bit-identical. Rings (~never at GG=32) = R7-proven fallback.
__global__ __launch_bounds__(256, 1) void knn_gemm1_kernel(const float4* __restrict__ sorted,
                                                           const unsigned* __restrict__ cstart,
                                                           const float* __restrict__ c,
                                                           int* __restrict__ nbr,
                                                           float* __restrict__ de,
                                                           unsigned* __restrict__ gmm,
                                                           const float* __restrict__ xa_,
                                                           const float* __restrict__ w1,
                                                           float* __restrict__ xw1) {
#pragma clang fp contract(off)
  if (blockIdx.x >= KNNB) {
    // ---- gemm1: xw1 = x @ W1, KIN=32, 4 features/thread (R1-verbatim, proven)
    int gid = (blockIdx.x - KNNB) * 256 + threadIdx.x;   // NN*16 total
    int i = gid >> 4, fq = gid & 15;
    const float4* ar = (const float4*)(xa_ + i * FIN);
    float4 A[FIN/4];
#pragma unroll
    for (int qq = 0; qq < FIN/4; ++qq) A[qq] = ar[qq];
    float4 acc = make_float4(0.f, 0.f, 0.f, 0.f);
#pragma unroll
    for (int k = 0; k < FIN; ++k) {
      float av = ((const float*)A)[k];
      float4 wv4 = *(const float4*)(w1 + k*HH + 4*fq);
      acc.x = fmaf(av, wv4.x, acc.x);
      acc.y = fmaf(av, wv4.y, acc.y);
      acc.z = fmaf(av, wv4.z, acc.z);
      acc.w = fmaf(av, wv4.w, acc.w);
    }
    *(float4*)(xw1 + i*HH + 4*fq) = acc;
    return;
  }

  const int g = blockIdx.x * 256 + threadIdx.x;
  const int t = g >> 2;                            // sorted node index
  const int q = g & 3;                             // quad lane
  const int lane = threadIdx.x & 63;
  const float4 me = sorted[t];
  const int myid = (int)__float_as_uint(me.w);
  const float h = 1.0f / GG;                       // exact 2^-5
  int cx = (int)(me.x * GG); cx = cx > GG-1 ? GG-1 : (cx < 0 ? 0 : cx);
  int cy = (int)(me.y * GG); cy = cy > GG-1 ? GG-1 : (cy < 0 ? 0 : cy);

  unsigned long long kd[KK];
#pragma unroll
  for (int m = 0; m < KK; ++m) kd[m] = ~0ull;

  auto process = [&](float4 cand) {
    int j = (int)__float_as_uint(cand.w);
    float xprod = me.x * cand.x;                       // round(x_i*x_j)
    float dot   = __builtin_fmaf(me.y, cand.y, xprod); // BLAS K=2 fma
    float S     = me.z + cand.z;                       // round(sq_i+sq_j)
    float twod  = dot + dot;                           // exact *2
    float d2    = S - twod;                            // one rounding
    unsigned ub = __float_as_uint(d2);
    ub = (ub & 0x80000000u) ? ~ub : (ub | 0x80000000u);
    unsigned long long key = ((unsigned long long)ub << 32) | (unsigned)j;
    if (j != myid && key < kd[KK-1]) {
      unsigned long long ck = key;
#pragma unroll
      for (int m = 0; m < KK; ++m) {
        bool sw = ck < kd[m];
        unsigned long long lo = sw ? ck : kd[m];
        unsigned long long hi = sw ? kd[m] : ck;
        kd[m] = lo; ck = hi;
      }
    }
  };

  // ---- 3x3 rect as one flat prefetched stream (branch-free consume)
  int lxa = cx-1 < 0 ? 0 : cx-1;
  int lxb = cx+1 > GG-1 ? GG-1 : cx+1;
  int lya = cy-1 < 0 ? 0 : cy-1;
  int lyb = cy+1 > GG-1 ? GG-1 : cy+1;
  unsigned b0, l0, b1, l1, b2, l2;
  {
    int nr = lyb - lya + 1;                        // 2 or 3
    unsigned s0 = cstart[lya*GG + lxa];
    unsigned e0 = cstart[lya*GG + lxb + 1];
    unsigned s1 = cstart[(lya+1)*GG + lxa];
    unsigned e1 = cstart[(lya+1)*GG + lxb + 1];
    unsigned s2 = (nr > 2) ? cstart[(lya+2)*GG + lxa] : 0u;
    unsigned e2 = (nr > 2) ? cstart[(lya+2)*GG + lxb + 1] : 0u;
    b0 = s0; l0 = e0 - s0;
    b1 = s1; l1 = e1 - s1;
    b2 = s2; l2 = e2 - s2;                         // 0 when nr==2
  }
  const unsigned c01 = l0 + l1;
  const unsigned T = c01 + l2;
  auto mapAddr = [&](unsigned idx) -> unsigned {   // idx < T
    unsigned a = b0 + idx;
    unsigned a1 = b1 + (idx - l0);
    unsigned a2 = b2 + (idx - c01);
    a = (idx >= l0) ? a1 : a;
    a = (idx >= c01) ? a2 : a;
    return a;
  };
  {
    float4 A[PF];
#pragma unroll
    for (int d = 0; d < PF; ++d) {
      unsigned idx = (unsigned)q + 4u*d;
      unsigned a = (idx < T) ? mapAddr(idx) : 0u;  // dummy addr for padding slots
      float4 v = sorted[a];
      if (idx >= T) v.w = me.w;                    // sentinel: j==myid -> rejected
      A[d] = v;
    }
#pragma unroll
    for (int d = 0; d < PF; ++d) process(A[d]);    // unconditional, branch-free
    // rare overflow (T>64): continue same mod-4 partition, no duplicates
    unsigned idx = 4u*PF + (unsigned)q;
#pragma unroll 1
    while (idx < T) { process(sorted[mapAddr(idx)]); idx += 4u; }
  }

  // ---- ring expansion with exact count-based stop (R7-proven; ~never fires)
  auto scanSpan = [&](unsigned p0, unsigned p1) {
    unsigned pp = p0 + (unsigned)q;
    if (pp >= p1) return;
    float4 cur = sorted[pp];
    unsigned pn = pp + 4;
#pragma unroll 1
    while (pn < p1) {
      float4 nxt = sorted[pn];
      process(cur);
      cur = nxt;
      pn += 4;
    }
    process(cur);
  };
  int R = 1;
  while (true) {
    bool whole = (lxa <= 0) && (lxb >= GG-1) && (lya <= 0) && (lyb >= GG-1);
    bool done = whole;
    if (!done) {
      float edge = 1e30f;
      if (lxa > 0)    edge = fminf(edge, me.x - (float)lxa * h);
      if (lxb < GG-1) edge = fminf(edge, (float)(lxb+1) * h - me.x);
      if (lya > 0)    edge = fminf(edge, me.y - (float)lya * h);
      if (lyb < GG-1) edge = fminf(edge, (float)(lyb+1) * h - me.y);
      float lim = edge * edge - 1e-5f;             // margin >> Gram noise (~1e-6)
      if (lim > 0.0f) {
        unsigned lb = __float_as_uint(lim) | 0x80000000u;   // map(lim), lim>0
        int cle = 0;
#pragma unroll
        for (int m = 0; m < KK; ++m) cle += ((unsigned)(kd[m] >> 32) <= lb) ? 1 : 0;
        cle += __shfl_xor(cle, 1, 64);
        cle += __shfl_xor(cle, 2, 64);
        done = cle >= KK;
      }
    }
    if (done) break;
    ++R;
    int nxa = cx-R < 0 ? 0 : cx-R;
    int nxb = cx+R > GG-1 ? GG-1 : cx+R;
    int nya = cy-R < 0 ? 0 : cy-R;
    int nyb = cy+R > GG-1 ? GG-1 : cy+R;
    // new top/bottom rows
#pragma unroll 1
    for (int rr = 0; rr < 2; ++rr) {
      int y = rr ? nyb : nya;
      bool has = rr ? (nyb > lyb) : (nya < lya);
      if (has) {
        unsigned p0 = cstart[y*GG + nxa];
        unsigned p1 = cstart[y*GG + nxb + 1];
        scanSpan(p0, p1);
      }
    }
    // new left/right columns
#pragma unroll 1
    for (int ss = 0; ss < 2; ++ss) {
      int xcol = ss ? nxb : nxa;
      bool has = ss ? (nxb > lxb) : (nxa < lxa);
      if (has) {
        unsigned bb0 = cstart[lya*GG + xcol];
        unsigned bb1 = cstart[lya*GG + xcol + 1];
#pragma unroll 1
        for (int y = lya; y <= lyb; ++y) {
          unsigned n0 = 0, n1 = 0;
          if (y < lyb) { n0 = cstart[(y+1)*GG + xcol]; n1 = cstart[(y+1)*GG + xcol + 1]; }
          scanSpan(bb0, bb1);
          bb0 = n0; bb1 = n1;
        }
      }
    }
    lxa = nxa; lxb = nxb; lya = nya; lyb = nyb;
  }

  // ---- merge 4 sorted per-lane lists -> global top-16 (keys unique via j bits)
  unsigned res[4];
#pragma unroll 1
  for (int r = 0; r < KK; ++r) {
    unsigned long long md = kd[0];
    unsigned long long m1 = __shfl_xor(md, 1, 64); md = m1 < md ? m1 : md;
    unsigned long long m2 = __shfl_xor(md, 2, 64); md = m2 < md ? m2 : md;
    if (kd[0] == md) {                              // unique winner lane pops
#pragma unroll
      for (int m = 0; m < KK-1; ++m) kd[m] = kd[m+1];
      kd[KK-1] = ~0ull;
    }
    if ((r >> 2) == q) res[r & 3] = (unsigned)(md & 0xFFFFFFFFull);
  }

  // ---- write nbr + edge epilogue (identical ops to passing rounds)
  int4 w4; w4.x = (int)res[0]; w4.y = (int)res[1]; w4.z = (int)res[2]; w4.w = (int)res[3];
  *(int4*)(nbr + myid*KK + 4*q) = w4;
  unsigned bmin = 0xFFFFFFFFu, bmax = 0u;
#pragma unroll
  for (int e = 0; e < 4; ++e) {
    int j = (int)res[e];
    float dx = me.x - c[2*j];
    float dy = me.y - c[2*j+1];
    float xx = dx * dx;
    float yy = dy * dy;
    float d  = __builtin_sqrtf(xx + yy);
    de[myid*KK + 4*q + e] = d;
    unsigned bb = __float_as_uint(d);               // d >= 0: bit order == float order
    bmin = bmin < bb ? bmin : bb;
    bmax = bmax > bb ? bmax : bb;
  }
#pragma unroll
  for (int off = 32; off > 0; off >>= 1) {
    unsigned ob = __shfl_xor(bmin, off, 64);
    bmin = bmin < ob ? bmin : ob;
    unsigned oB = __shfl_xor(bmax, off, 64);
    bmax = bmax > oB ? bmax : oB;
  }
  if (lane == 0) {
    atomicMin(&gmm[0], bmin);
    atomicMax(&gmm[1], bmax);
  }
}

// ---------------------------------------------------------------- ew + deg + dis
__global__ __launch_bounds__(256) void ewdeg_kernel(const unsigned* __restrict__ gmm,
                                                    float* __restrict__ de,   // in: d, out: ew
                                                    float* __restrict__ dis) {
#pragma clang fp contract(off)
  int i = blockIdx.x * 256 + threadIdx.x;
  if (i >= NN) return;
  float mx  = __uint_as_float(gmm[1]);
  float rng = mx - __uint_as_float(gmm[0]);
  float deg = 0.0f;                         // edges first, self-loop last (segment_sum order)
  float4* dp = (float4*)(de + i*KK);
#pragma unroll
  for (int qq = 0; qq < 4; ++qq) {
    float4 v = dp[qq];
    float e0 = (mx - v.x) / rng;
    float e1 = (mx - v.y) / rng;
    float e2 = (mx - v.z) / rng;
    float e3 = (mx - v.w) / rng;
    deg = deg + e0; deg = deg + e1;
    deg = deg + e2; deg = deg + e3;
    dp[qq] = make_float4(e0, e1, e2, e3);
  }
  deg = deg + 1.0f;                         // self-loop weight 1, added last
  dis[i] = 1.0f / __builtin_sqrtf(deg);     // deg >= 1
}

// ---------------------------------------------------------------- agg1 + relu + gemm2 fused
__global__ __launch_bounds__(256) void agg_gemm2_kernel(const float* __restrict__ xw,
                                                        const int* __restrict__ nbr,
                                                        const float* __restrict__ ew,
                                                        const float* __restrict__ dis,
                                                        const float* __restrict__ b,
                                                        const int* __restrict__ sid,
                                                        const float* __restrict__ w2,
                                                        float* __restrict__ xw2) {
  int wv = threadIdx.x >> 6, lane = threadIdx.x & 63;
  int i = sid[(blockIdx.x << 2) + wv];
  float di = dis[i];
  float acc = 0.0f;
#pragma unroll 4
  for (int k = 0; k < KK; ++k) {
    int s = nbr[i*KK + k];
    float coef = (dis[s] * ew[i*KK + k]) * di;   // (dis[s]*w)*dis[t]
    acc = fmaf(coef, xw[s*HH + lane], acc);
  }
  acc = fmaf(di * di, xw[i*HH + lane], acc);     // self loop last
  float hv = fmaxf(acc + b[lane], 0.0f);         // h1[i][lane]
  float acc2 = 0.0f;
#pragma unroll 16
  for (int k = 0; k < HH; ++k) {
    float hk = __shfl(hv, k, 64);
    acc2 = fmaf(hk, w2[k*HH + lane], acc2);
  }
  xw2[i*HH + lane] = acc2;
}

// ---------------------------------------------------------------- agg2 + relu + fc (final)
__global__ __launch_bounds__(256) void agg_fc_kernel(const float* __restrict__ xw,
                                                     const int* __restrict__ nbr,
                                                     const float* __restrict__ ew,
                                                     const float* __restrict__ dis,
                                                     const float* __restrict__ b,
                                                     const float* __restrict__ wfc,
                                                     const float* __restrict__ bfc,
                                                     const int* __restrict__ sid,
                                                     float* __restrict__ out) {
  int wv = threadIdx.x >> 6, lane = threadIdx.x & 63;
  int i = sid[(blockIdx.x << 2) + wv];
  float di = dis[i];
  float acc = 0.0f;
#pragma unroll 4
  for (int k = 0; k < KK; ++k) {
    int s = nbr[i*KK + k];
    float coef = (dis[s] * ew[i*KK + k]) * di;
    acc = fmaf(coef, xw[s*HH + lane], acc);
  }
  acc = fmaf(di * di, xw[i*HH + lane], acc);
  float v = fmaxf(acc + b[lane], 0.0f);             // h2 feature
  float p = v * wfc[lane];                          // h2 @ Wfc  (F_OUT = 1)
#pragma unroll
  for (int off = 32; off > 0; off >>= 1) p = p + __shfl_xor(p, off, 64);
  if (lane == 0) out[i] = p + bfc[0];
}

// ---------------------------------------------------------------- launch
extern "C" void kernel_launch(void* const* d_in, const int* in_sizes, int n_in,
                              void* d_out, int out_size, void* d_ws, size_t ws_size,
                              hipStream_t stream) {
  (void)in_sizes; (void)n_in; (void)out_size; (void)ws_size;
  const float* x   = (const float*)d_in[0];
  const float* c   = (const float*)d_in[1];
  const float* W1  = (const float*)d_in[2];
  const float* b1  = (const float*)d_in[3];
  const float* W2  = (const float*)d_in[4];
  const float* b2  = (const float*)d_in[5];
  const float* Wfc = (const float*)d_in[6];
  const float* bfc = (const float*)d_in[7];
  float* out = (float*)d_out;

  char* ws = (char*)d_ws;
  size_t off = 0;
  auto alloc = [&](size_t bytes) -> void* {
    void* p = ws + off;
    off += (bytes + 255) & ~size_t(255);
    return p;
  };
  float4*   pack   = (float4*)  alloc(NN * sizeof(float4));       // 256 KB
  float4*   sorted = (float4*)  alloc(NN * sizeof(float4));       // 256 KB
  unsigned* cnt    = (unsigned*)alloc(NCELL * sizeof(unsigned));  // 4 KB
  unsigned* cstart = (unsigned*)alloc((NCELL+1) * sizeof(unsigned));
  unsigned* cellid = (unsigned*)alloc(NN * sizeof(unsigned));     // 64 KB
  int*      sid    = (int*)     alloc(NN * sizeof(int));          // 64 KB
  int*      nbr    = (int*)     alloc(NE * sizeof(int));          // 1 MB
  float*    ew     = (float*)   alloc(NE * sizeof(float));        // 1 MB (d then ew in-place)
  float*    dis    = (float*)   alloc(NN * sizeof(float));        // 64 KB
  unsigned* gmm    = (unsigned*)alloc(2 * sizeof(unsigned));
  float*    xw1    = (float*)   alloc(NN * HH * sizeof(float));   // 4 MB
  float*    xw2    = (float*)   alloc(NN * HH * sizeof(float));   // 4 MB

  const int NB = (NN + 255) / 256;
  hipMemsetAsync(cnt, 0, NCELL * sizeof(unsigned), stream);
  prep_count_kernel<<<NB,   256, 0, stream>>>(c, pack, cellid, cnt, gmm);
  scatter_kernel   <<<NB,   256, 0, stream>>>(pack, cellid, cnt, cstart, sorted, sid);
  knn_gemm1_kernel <<<KNNB + GEMM1B, 256, 0, stream>>>(sorted, cstart, c, nbr, ew, gmm,
                                                       x, W1, xw1);
  ewdeg_kernel     <<<NB,   256, 0, stream>>>(gmm, ew, dis);
  agg_gemm2_kernel <<<NN/4, 256, 0, stream>>>(xw1, nbr, ew, dis, b1, sid, W2, xw2);
  agg_fc_kernel    <<<NN/4, 256, 0, stream>>>(xw2, nbr, ew, dis, b2, Wfc, bfc, sid, out);
}

// Round 12
// 138.604 us; speedup vs baseline: 4.4977x; 1.1051x over previous
//
#include <hip/hip_runtime.h>
#include <cstdint>

#define NN 16000
#define KK 16
#define FIN 32
#define HH 64
#define NE (NN*KK)
#define GG 32                    // 15.6 pts/cell; 3x3 rect -> stop-radius lambda~49 >> 16
#define NCELL (GG*GG)

#define KNNB 250                 // knn blocks: 64 nodes/block (4 lanes/node)
#define GEMM1B (NN*16/256)       // 1000 gemm1 blocks
#define NWAVE (KNNB*4)           // 1000 knn waves -> partial min/max slots

// ---------------------------------------------------------------- prep + count
// rank packed into cellid: cell in bits[9:0], rank in bits[31:10] (rank<16000)
__global__ __launch_bounds__(256) void prep_count_kernel(const float* __restrict__ c,
                                                         float4* __restrict__ pack,
                                                         unsigned* __restrict__ cellid,
                                                         unsigned* __restrict__ cnt) {
#pragma clang fp contract(off)
  int i = blockIdx.x * 256 + threadIdx.x;
  if (i >= NN) return;
  float xv = c[2*i], yv = c[2*i+1];
  float xx = xv * xv;            // round(x^2)  (no fma: contract off)
  float yy = yv * yv;            // round(y^2)
  float sq = xx + yy;            // round(xx+yy)
  pack[i] = make_float4(xv, yv, sq, __uint_as_float((unsigned)i));
  int cx = (int)(xv * GG); cx = cx > GG-1 ? GG-1 : (cx < 0 ? 0 : cx);
  int cy = (int)(yv * GG); cy = cy > GG-1 ? GG-1 : (cy < 0 ? 0 : cy);
  unsigned cell = (unsigned)(cy * GG + cx);
  unsigned rank = atomicAdd(&cnt[cell], 1u);
  cellid[i] = cell | (rank << 10);
}

// ---------------------------------------------------------------- scatter (atomic-free) + redundant LDS scan
// Each block scans the 1024-cell histogram into LDS (R8-phase-B-proven code);
// block 0 also publishes cstart for knn. Position = cs[cell] + rank.
__global__ __launch_bounds__(256) void scatter_kernel(const float4* __restrict__ pack,
                                                      const unsigned* __restrict__ cellid,
                                                      const unsigned* __restrict__ cnt,
                                                      unsigned* __restrict__ cstart,
                                                      float4* __restrict__ sorted,
                                                      int* __restrict__ sid) {
  __shared__ unsigned lds_cs[NCELL + 1];
  __shared__ unsigned wsum[4];
  const int tid = threadIdx.x;
  const int lane = tid & 63, wv = tid >> 6;
  {
    unsigned h0 = cnt[tid*4+0], h1 = cnt[tid*4+1], h2 = cnt[tid*4+2], h3 = cnt[tid*4+3];
    unsigned s = h0 + h1 + h2 + h3;
    unsigned v = s;
#pragma unroll
    for (int off = 1; off < 64; off <<= 1) {
      unsigned u = __shfl_up(v, off, 64);
      if (lane >= off) v += u;
    }
    if (lane == 63) wsum[wv] = v;
    __syncthreads();
    if (wv == 0) {
      unsigned t = (lane < 4) ? wsum[lane] : 0u;
      unsigned vv = t;
#pragma unroll
      for (int off = 1; off < 4; off <<= 1) {
        unsigned u = __shfl_up(vv, off, 64);
        if (lane >= off) vv += u;
      }
      if (lane < 4) wsum[lane] = vv - t;           // exclusive
    }
    __syncthreads();
    unsigned b = wsum[wv] + v - s;
    lds_cs[tid*4+0] = b; b += h0;
    lds_cs[tid*4+1] = b; b += h1;
    lds_cs[tid*4+2] = b; b += h2;
    lds_cs[tid*4+3] = b; b += h3;
    if (tid == 255) lds_cs[NCELL] = b;             // == NN
    __syncthreads();
    if (blockIdx.x == 0) {
      cstart[tid*4+0] = lds_cs[tid*4+0];
      cstart[tid*4+1] = lds_cs[tid*4+1];
      cstart[tid*4+2] = lds_cs[tid*4+2];
      cstart[tid*4+3] = lds_cs[tid*4+3];
      if (tid == 255) cstart[NCELL] = lds_cs[NCELL];
    }
  }
  int i = blockIdx.x * 256 + tid;
  if (i >= NN) return;
  unsigned cc = cellid[i];
  unsigned p = lds_cs[cc & 1023u] + (cc >> 10);
  sorted[p] = pack[i];                             // .w carries original index bits
  sid[p] = i;
}

// ---------------------------------------------------------------- knn (R7 body) + gemm1 backfill
// R11 post-mortem: the ONLY component never varied across 11 rounds is the
// gmm atomicMin/Max epilogue -- 2000 device-scope RMWs on 2 words from 1000
// waves serialize at the owning L2 (~50-150cy each, cross-XCD), and each
// wave drains vmcnt(0) before endpgm -> ~40-120us tail matching the
// invariant ~43-50us wall (R1's 4000 waves -> 105us = 2x, consistent).
// FIX: lane 0 plain-stores its wave's {bmin,bmax} to part[waveId] (1000
// independent 8B stores, zero contention); ewdeg reduces the array. Values
// reduced are identical -> mx/rng bit-identical. knn body = R7-proven.
__global__ __launch_bounds__(256) void knn_gemm1_kernel(const float4* __restrict__ sorted,
                                                        const unsigned* __restrict__ cstart,
                                                        const float* __restrict__ c,
                                                        int* __restrict__ nbr,
                                                        float* __restrict__ de,
                                                        uint2* __restrict__ part,
                                                        const float* __restrict__ xa_,
                                                        const float* __restrict__ w1,
                                                        float* __restrict__ xw1) {
#pragma clang fp contract(off)
  if (blockIdx.x >= KNNB) {
    // ---- gemm1: xw1 = x @ W1, KIN=32, 4 features/thread (R1-verbatim, proven)
    int gid = (blockIdx.x - KNNB) * 256 + threadIdx.x;   // NN*16 total
    int i = gid >> 4, fq = gid & 15;
    const float4* ar = (const float4*)(xa_ + i * FIN);
    float4 A[FIN/4];
#pragma unroll
    for (int qq = 0; qq < FIN/4; ++qq) A[qq] = ar[qq];
    float4 acc = make_float4(0.f, 0.f, 0.f, 0.f);
#pragma unroll
    for (int k = 0; k < FIN; ++k) {
      float av = ((const float*)A)[k];
      float4 wv4 = *(const float4*)(w1 + k*HH + 4*fq);
      acc.x = fmaf(av, wv4.x, acc.x);
      acc.y = fmaf(av, wv4.y, acc.y);
      acc.z = fmaf(av, wv4.z, acc.z);
      acc.w = fmaf(av, wv4.w, acc.w);
    }
    *(float4*)(xw1 + i*HH + 4*fq) = acc;
    return;
  }

  const int g = blockIdx.x * 256 + threadIdx.x;
  const int t = g >> 2;                            // sorted node index
  const int q = g & 3;                             // quad lane
  const int lane = threadIdx.x & 63;
  const float4 me = sorted[t];
  const int myid = (int)__float_as_uint(me.w);
  const float h = 1.0f / GG;                       // exact 2^-5
  int cx = (int)(me.x * GG); cx = cx > GG-1 ? GG-1 : (cx < 0 ? 0 : cx);
  int cy = (int)(me.y * GG); cy = cy > GG-1 ? GG-1 : (cy < 0 ? 0 : cy);

  unsigned long long kd[KK];
#pragma unroll
  for (int m = 0; m < KK; ++m) kd[m] = ~0ull;

  auto process = [&](float4 cand) {
    int j = (int)__float_as_uint(cand.w);
    float xprod = me.x * cand.x;                       // round(x_i*x_j)
    float dot   = __builtin_fmaf(me.y, cand.y, xprod); // BLAS K=2 fma
    float S     = me.z + cand.z;                       // round(sq_i+sq_j)
    float twod  = dot + dot;                           // exact *2
    float d2    = S - twod;                            // one rounding
    unsigned ub = __float_as_uint(d2);
    ub = (ub & 0x80000000u) ? ~ub : (ub | 0x80000000u);
    unsigned long long key = ((unsigned long long)ub << 32) | (unsigned)j;
    if (j != myid && key < kd[KK-1]) {
      unsigned long long ck = key;
#pragma unroll
      for (int m = 0; m < KK; ++m) {
        bool sw = ck < kd[m];
        unsigned long long lo = sw ? ck : kd[m];
        unsigned long long hi = sw ? kd[m] : ck;
        kd[m] = lo; ck = hi;
      }
    }
  };
  // 2-deep pipelined span scan; instantiated at exactly 3 call sites
  auto scanSpan = [&](unsigned p0, unsigned p1) {
    unsigned pp = p0 + (unsigned)q;
    if (pp >= p1) return;
    float4 cur = sorted[pp];
    unsigned pn = pp + 4;
#pragma unroll 1
    while (pn < p1) {
      float4 nxt = sorted[pn];
      process(cur);
      cur = nxt;
      pn += 4;
    }
    process(cur);
  };

  // ---- initial 3x3 rect (site 1): row bounds software-pipelined
  int lxa = cx-1 < 0 ? 0 : cx-1;
  int lxb = cx+1 > GG-1 ? GG-1 : cx+1;
  int lya = cy-1 < 0 ? 0 : cy-1;
  int lyb = cy+1 > GG-1 ? GG-1 : cy+1;
  {
    unsigned b0 = cstart[lya*GG + lxa];
    unsigned b1 = cstart[lya*GG + lxb + 1];
#pragma unroll 1
    for (int y = lya; y <= lyb; ++y) {
      unsigned n0 = 0, n1 = 0;
      if (y < lyb) { n0 = cstart[(y+1)*GG + lxa]; n1 = cstart[(y+1)*GG + lxb + 1]; }
      scanSpan(b0, b1);
      b0 = n0; b1 = n1;
    }
  }

  // ---- ring expansion with exact count-based stop (validated; generic in h)
  int R = 1;
  while (true) {
    bool whole = (lxa <= 0) && (lxb >= GG-1) && (lya <= 0) && (lyb >= GG-1);
    bool done = whole;
    if (!done) {
      float edge = 1e30f;
      if (lxa > 0)    edge = fminf(edge, me.x - (float)lxa * h);
      if (lxb < GG-1) edge = fminf(edge, (float)(lxb+1) * h - me.x);
      if (lya > 0)    edge = fminf(edge, me.y - (float)lya * h);
      if (lyb < GG-1) edge = fminf(edge, (float)(lyb+1) * h - me.y);
      float lim = edge * edge - 1e-5f;             // margin >> Gram noise (~1e-6)
      if (lim > 0.0f) {
        unsigned lb = __float_as_uint(lim) | 0x80000000u;   // map(lim), lim>0
        int cle = 0;
#pragma unroll
        for (int m = 0; m < KK; ++m) cle += ((unsigned)(kd[m] >> 32) <= lb) ? 1 : 0;
        cle += __shfl_xor(cle, 1, 64);
        cle += __shfl_xor(cle, 2, 64);
        done = cle >= KK;
      }
    }
    if (done) break;
    ++R;
    int nxa = cx-R < 0 ? 0 : cx-R;
    int nxb = cx+R > GG-1 ? GG-1 : cx+R;
    int nya = cy-R < 0 ? 0 : cy-R;
    int nyb = cy+R > GG-1 ? GG-1 : cy+R;
    // new top/bottom rows (site 2)
#pragma unroll 1
    for (int rr = 0; rr < 2; ++rr) {
      int y = rr ? nyb : nya;
      bool has = rr ? (nyb > lyb) : (nya < lya);
      if (has) {
        unsigned p0 = cstart[y*GG + nxa];
        unsigned p1 = cstart[y*GG + nxb + 1];
        scanSpan(p0, p1);
      }
    }
    // new left/right columns (site 3): per-cell spans, bounds pipelined
#pragma unroll 1
    for (int ss = 0; ss < 2; ++ss) {
      int xcol = ss ? nxb : nxa;
      bool has = ss ? (nxb > lxb) : (nxa < lxa);
      if (has) {
        unsigned b0 = cstart[lya*GG + xcol];
        unsigned b1 = cstart[lya*GG + xcol + 1];
#pragma unroll 1
        for (int y = lya; y <= lyb; ++y) {
          unsigned n0 = 0, n1 = 0;
          if (y < lyb) { n0 = cstart[(y+1)*GG + xcol]; n1 = cstart[(y+1)*GG + xcol + 1]; }
          scanSpan(b0, b1);
          b0 = n0; b1 = n1;
        }
      }
    }
    lxa = nxa; lxb = nxb; lya = nya; lyb = nyb;
  }

  // ---- merge 4 sorted per-lane lists -> global top-16 (keys unique via j bits)
  unsigned res[4];
#pragma unroll 1
  for (int r = 0; r < KK; ++r) {
    unsigned long long md = kd[0];
    unsigned long long m1 = __shfl_xor(md, 1, 64); md = m1 < md ? m1 : md;
    unsigned long long m2 = __shfl_xor(md, 2, 64); md = m2 < md ? m2 : md;
    if (kd[0] == md) {                              // unique winner lane pops
#pragma unroll
      for (int m = 0; m < KK-1; ++m) kd[m] = kd[m+1];
      kd[KK-1] = ~0ull;
    }
    if ((r >> 2) == q) res[r & 3] = (unsigned)(md & 0xFFFFFFFFull);
  }

  // ---- write nbr + edge epilogue; wave min/max -> plain store (NO atomics)
  int4 w4; w4.x = (int)res[0]; w4.y = (int)res[1]; w4.z = (int)res[2]; w4.w = (int)res[3];
  *(int4*)(nbr + myid*KK + 4*q) = w4;
  unsigned bmin = 0xFFFFFFFFu, bmax = 0u;
#pragma unroll
  for (int e = 0; e < 4; ++e) {
    int j = (int)res[e];
    float dx = me.x - c[2*j];
    float dy = me.y - c[2*j+1];
    float xx = dx * dx;
    float yy = dy * dy;
    float d  = __builtin_sqrtf(xx + yy);
    de[myid*KK + 4*q + e] = d;
    unsigned bb = __float_as_uint(d);               // d >= 0: bit order == float order
    bmin = bmin < bb ? bmin : bb;
    bmax = bmax > bb ? bmax : bb;
  }
#pragma unroll
  for (int off = 32; off > 0; off >>= 1) {
    unsigned ob = __shfl_xor(bmin, off, 64);
    bmin = bmin < ob ? bmin : ob;
    unsigned oB = __shfl_xor(bmax, off, 64);
    bmax = bmax > oB ? bmax : oB;
  }
  if (lane == 0) part[g >> 6] = make_uint2(bmin, bmax);   // wave id in [0,1000)
}

// ---------------------------------------------------------------- ew + deg + dis (+ partial min/max reduce)
// Every block redundantly reduces the 1000-entry partial array (8 KB, L2-hot)
// with integer min/max -> mx/rng bit-identical to the old gmm atomics.
__global__ __launch_bounds__(256) void ewdeg_kernel(const uint2* __restrict__ part,
                                                    float* __restrict__ de,   // in: d, out: ew
                                                    float* __restrict__ dis) {
#pragma clang fp contract(off)
  __shared__ unsigned smn[4], smx[4];
  const int tid = threadIdx.x;
  const int lane = tid & 63, wv = tid >> 6;
  unsigned mn = 0xFFFFFFFFu, mxb = 0u;
  for (int j = tid; j < NWAVE; j += 256) {
    uint2 p = part[j];
    mn  = mn  < p.x ? mn  : p.x;
    mxb = mxb > p.y ? mxb : p.y;
  }
#pragma unroll
  for (int off = 32; off > 0; off >>= 1) {
    unsigned om = __shfl_xor(mn, off, 64);
    mn = mn < om ? mn : om;
    unsigned ox = __shfl_xor(mxb, off, 64);
    mxb = mxb > ox ? mxb : ox;
  }
  if (lane == 0) { smn[wv] = mn; smx[wv] = mxb; }
  __syncthreads();
  mn  = smn[0]; mxb = smx[0];
#pragma unroll
  for (int k = 1; k < 4; ++k) {
    mn  = mn  < smn[k] ? mn  : smn[k];
    mxb = mxb > smx[k] ? mxb : smx[k];
  }

  int i = blockIdx.x * 256 + tid;
  if (i >= NN) return;
  float mx  = __uint_as_float(mxb);
  float rng = mx - __uint_as_float(mn);
  float deg = 0.0f;                         // edges first, self-loop last (segment_sum order)
  float4* dp = (float4*)(de + i*KK);
#pragma unroll
  for (int qq = 0; qq < 4; ++qq) {
    float4 v = dp[qq];
    float e0 = (mx - v.x) / rng;
    float e1 = (mx - v.y) / rng;
    float e2 = (mx - v.z) / rng;
    float e3 = (mx - v.w) / rng;
    deg = deg + e0; deg = deg + e1;
    deg = deg + e2; deg = deg + e3;
    dp[qq] = make_float4(e0, e1, e2, e3);
  }
  deg = deg + 1.0f;                         // self-loop weight 1, added last
  dis[i] = 1.0f / __builtin_sqrtf(deg);     // deg >= 1
}

// ---------------------------------------------------------------- agg1 + relu + gemm2 fused
__global__ __launch_bounds__(256) void agg_gemm2_kernel(const float* __restrict__ xw,
                                                        const int* __restrict__ nbr,
                                                        const float* __restrict__ ew,
                                                        const float* __restrict__ dis,
                                                        const float* __restrict__ b,
                                                        const int* __restrict__ sid,
                                                        const float* __restrict__ w2,
                                                        float* __restrict__ xw2) {
  int wv = threadIdx.x >> 6, lane = threadIdx.x & 63;
  int i = sid[(blockIdx.x << 2) + wv];
  float di = dis[i];
  float acc = 0.0f;
#pragma unroll 4
  for (int k = 0; k < KK; ++k) {
    int s = nbr[i*KK + k];
    float coef = (dis[s] * ew[i*KK + k]) * di;   // (dis[s]*w)*dis[t]
    acc = fmaf(coef, xw[s*HH + lane], acc);
  }
  acc = fmaf(di * di, xw[i*HH + lane], acc);     // self loop last
  float hv = fmaxf(acc + b[lane], 0.0f);         // h1[i][lane]
  float acc2 = 0.0f;
#pragma unroll 16
  for (int k = 0; k < HH; ++k) {
    float hk = __shfl(hv, k, 64);
    acc2 = fmaf(hk, w2[k*HH + lane], acc2);
  }
  xw2[i*HH + lane] = acc2;
}

// ---------------------------------------------------------------- agg2 + relu + fc (final)
__global__ __launch_bounds__(256) void agg_fc_kernel(const float* __restrict__ xw,
                                                     const int* __restrict__ nbr,
                                                     const float* __restrict__ ew,
                                                     const float* __restrict__ dis,
                                                     const float* __restrict__ b,
                                                     const float* __restrict__ wfc,
                                                     const float* __restrict__ bfc,
                                                     const int* __restrict__ sid,
                                                     float* __restrict__ out) {
  int wv = threadIdx.x >> 6, lane = threadIdx.x & 63;
  int i = sid[(blockIdx.x << 2) + wv];
  float di = dis[i];
  float acc = 0.0f;
#pragma unroll 4
  for (int k = 0; k < KK; ++k) {
    int s = nbr[i*KK + k];
    float coef = (dis[s] * ew[i*KK + k]) * di;
    acc = fmaf(coef, xw[s*HH + lane], acc);
  }
  acc = fmaf(di * di, xw[i*HH + lane], acc);
  float v = fmaxf(acc + b[lane], 0.0f);             // h2 feature
  float p = v * wfc[lane];                          // h2 @ Wfc  (F_OUT = 1)
#pragma unroll
  for (int off = 32; off > 0; off >>= 1) p = p + __shfl_xor(p, off, 64);
  if (lane == 0) out[i] = p + bfc[0];
}

// ---------------------------------------------------------------- launch
extern "C" void kernel_launch(void* const* d_in, const int* in_sizes, int n_in,
                              void* d_out, int out_size, void* d_ws, size_t ws_size,
                              hipStream_t stream) {
  (void)in_sizes; (void)n_in; (void)out_size; (void)ws_size;
  const float* x   = (const float*)d_in[0];
  const float* c   = (const float*)d_in[1];
  const float* W1  = (const float*)d_in[2];
  const float* b1  = (const float*)d_in[3];
  const float* W2  = (const float*)d_in[4];
  const float* b2  = (const float*)d_in[5];
  const float* Wfc = (const float*)d_in[6];
  const float* bfc = (const float*)d_in[7];
  float* out = (float*)d_out;

  char* ws = (char*)d_ws;
  size_t off = 0;
  auto alloc = [&](size_t bytes) -> void* {
    void* p = ws + off;
    off += (bytes + 255) & ~size_t(255);
    return p;
  };
  float4*   pack   = (float4*)  alloc(NN * sizeof(float4));       // 256 KB
  float4*   sorted = (float4*)  alloc(NN * sizeof(float4));       // 256 KB
  unsigned* cnt    = (unsigned*)alloc(NCELL * sizeof(unsigned));  // 4 KB
  unsigned* cstart = (unsigned*)alloc((NCELL+1) * sizeof(unsigned));
  unsigned* cellid = (unsigned*)alloc(NN * sizeof(unsigned));     // 64 KB
  int*      sid    = (int*)     alloc(NN * sizeof(int));          // 64 KB
  int*      nbr    = (int*)     alloc(NE * sizeof(int));          // 1 MB
  float*    ew     = (float*)   alloc(NE * sizeof(float));        // 1 MB (d then ew in-place)
  float*    dis    = (float*)   alloc(NN * sizeof(float));        // 64 KB
  uint2*    part   = (uint2*)   alloc(NWAVE * sizeof(uint2));     // 8 KB wave partials
  float*    xw1    = (float*)   alloc(NN * HH * sizeof(float));   // 4 MB
  float*    xw2    = (float*)   alloc(NN * HH * sizeof(float));   // 4 MB

  const int NB = (NN + 255) / 256;
  hipMemsetAsync(cnt, 0, NCELL * sizeof(unsigned), stream);
  prep_count_kernel<<<NB,   256, 0, stream>>>(c, pack, cellid, cnt);
  scatter_kernel   <<<NB,   256, 0, stream>>>(pack, cellid, cnt, cstart, sorted, sid);
  knn_gemm1_kernel <<<KNNB + GEMM1B, 256, 0, stream>>>(sorted, cstart, c, nbr, ew, part,
                                                       x, W1, xw1);
  ewdeg_kernel     <<<NB,   256, 0, stream>>>(part, ew, dis);
  agg_gemm2_kernel <<<NN/4, 256, 0, stream>>>(xw1, nbr, ew, dis, b1, sid, W2, xw2);
  agg_fc_kernel    <<<NN/4, 256, 0, stream>>>(xw2, nbr, ew, dis, b2, Wfc, bfc, sid, out);
}